// Round 1
// baseline (346.014 us; speedup 1.0000x reference)
//
#include <hip/hip_runtime.h>

// Per-element MLP: 1 -> 32 -> (32x32) x 9 -> 1, leaky relu (slope 0.01).
// Round 1: correct fp32 baseline. Thread-per-element; weights are wave-uniform
// loads (s_load via __restrict__ + uniform indices) feeding v_fma with SGPR
// operands. h/acc live in VGPRs (~80 -> 4 waves/SIMD).
// Expected: VALU-bound at ~124us (19.5 GFLOP / 157 TF fp32 vector).

#define N_HIDDEN_LAYERS 9
#define HID 32
#define SLOPE 0.01f

__device__ __forceinline__ float leaky(float v) {
    // slope < 1: leaky(v) = max(v, slope*v)
    return fmaxf(v, SLOPE * v);
}

__global__ __launch_bounds__(256) void mlp_fp32_kernel(
    const float* __restrict__ x,      // [N]
    const float* __restrict__ W_in,   // [1,32]
    const float* __restrict__ b_in,   // [32]
    const float* __restrict__ W_hid,  // [9,32,32] (k-major: W[l][k][n])
    const float* __restrict__ b_hid,  // [9,32]
    const float* __restrict__ W_out,  // [32,1]
    const float* __restrict__ b_out,  // [1]
    float* __restrict__ out,          // [N]
    int N)
{
    int i = blockIdx.x * blockDim.x + threadIdx.x;
    if (i >= N) return;

    float xv = x[i];

    float h[HID];
#pragma unroll
    for (int n = 0; n < HID; ++n)
        h[n] = leaky(fmaf(xv, W_in[n], b_in[n]));

    // Hidden layers: k-outer / n-inner so W[l][k][0..31] is a contiguous,
    // wave-uniform 128B row -> s_load_dwordx16 pairs; FMAs take SGPR operand.
#pragma unroll 1
    for (int l = 0; l < N_HIDDEN_LAYERS; ++l) {
        const float* __restrict__ W = W_hid + l * HID * HID;
        const float* __restrict__ b = b_hid + l * HID;

        float acc[HID];
#pragma unroll
        for (int n = 0; n < HID; ++n) acc[n] = b[n];

#pragma unroll
        for (int k = 0; k < HID; ++k) {
            float hk = h[k];
            const float* __restrict__ Wrow = W + k * HID;
#pragma unroll
            for (int n = 0; n < HID; ++n)
                acc[n] = fmaf(hk, Wrow[n], acc[n]);
        }

#pragma unroll
        for (int n = 0; n < HID; ++n) h[n] = leaky(acc[n]);
    }

    float o = b_out[0];
#pragma unroll
    for (int k = 0; k < HID; ++k)
        o = fmaf(h[k], W_out[k], o);

    out[i] = o;
}

extern "C" void kernel_launch(void* const* d_in, const int* in_sizes, int n_in,
                              void* d_out, int out_size, void* d_ws, size_t ws_size,
                              hipStream_t stream) {
    const float* x     = (const float*)d_in[0];
    const float* W_in  = (const float*)d_in[1];
    const float* b_in  = (const float*)d_in[2];
    const float* W_hid = (const float*)d_in[3];
    const float* b_hid = (const float*)d_in[4];
    const float* W_out = (const float*)d_in[5];
    const float* b_out = (const float*)d_in[6];
    float* out = (float*)d_out;

    int N = in_sizes[0];
    dim3 block(256);
    dim3 grid((N + 255) / 256);
    mlp_fp32_kernel<<<grid, block, 0, stream>>>(x, W_in, b_in, W_hid, b_hid,
                                                W_out, b_out, out, N);
}

// Round 3
// 122.272 us; speedup vs baseline: 2.8299x; 2.8299x over previous
//
#include <hip/hip_runtime.h>

// Per-element MLP 1->32->(32x32)x9->1, leaky relu, via v_mfma_f32_32x32x16_f16.
// Formulation: H'^T = leaky(W^T H^T + b). Activations live in the B operand
// (col = batch = lane&31); output lands in C layout with the SAME batch->lane
// mapping. A hidden-unit permutation q() applied to the weight input side makes
// C reg r == B slot r, so the inter-layer transform is just cvt_pkrtz + pk-leaky
// (no cross-lane data movement at all).
// Bias is the MFMA C-operand (free add), staged permuted in LDS.
// All 9 layers' A-fragments resident in VGPRs (72 regs f16-packed).

#define NLAYERS 9
#define HID 32
#define SLOPE 0.01f

typedef _Float16 v2h __attribute__((ext_vector_type(2)));
typedef _Float16 v8h __attribute__((ext_vector_type(8)));
typedef float v16f __attribute__((ext_vector_type(16)));

// Packed f32->f16 (RTZ) returning our _Float16 vector type.
__device__ __forceinline__ v2h pk_cvt(float a, float b) {
    return __builtin_bit_cast(v2h, __builtin_amdgcn_cvt_pkrtz(a, b));
}

// B-operand physical slot k -> logical hidden unit (weight-side permutation)
__device__ __forceinline__ int qmap(int k) {
    int c = k >> 4, h = (k >> 3) & 1, t = k & 7;
    return 16 * c + 4 * h + (t & 3) + 8 * (t >> 2);
}
// C/D reg -> physical row (output side is identity arrangement)
__device__ __forceinline__ int rmap(int reg, int h) {
    return (reg & 3) + 8 * (reg >> 2) + 4 * h;
}

__global__ __launch_bounds__(256) void mlp_mfma_kernel(
    const float* __restrict__ x,
    const float* __restrict__ W_in,   // [1,32]
    const float* __restrict__ b_in,   // [32]
    const float* __restrict__ W_hid,  // [9,32,32]  W[l][k_in][n_out]
    const float* __restrict__ b_hid,  // [9,32]
    const float* __restrict__ W_out,  // [32,1]
    const float* __restrict__ b_out,  // [1]
    float* __restrict__ out, int N)
{
    __shared__ __align__(16) float bias_sh[NLAYERS][2][16];
    for (int t = threadIdx.x; t < NLAYERS * 32; t += blockDim.x) {
        int l = t >> 5, r = t & 31, h = r >> 4, reg = r & 15;
        bias_sh[l][h][reg] = b_hid[l * HID + rmap(reg, h)];
    }
    __syncthreads();

    const int lane = threadIdx.x & 63;
    const int half = lane >> 5;
    const int m    = lane & 31;   // batch col within tile; also A output-row

    // ---- resident weight fragments ----
    // A[m_out][k] = W_logical[q(k)][m_out]; lane holds k = 16c + 8*half + j
    v8h alo[NLAYERS], ahi[NLAYERS];
#pragma unroll
    for (int l = 0; l < NLAYERS; ++l) {
        const float* Wl = W_hid + l * HID * HID;
#pragma unroll
        for (int j = 0; j < 8; ++j) {
            alo[l][j] = (_Float16)Wl[qmap(8 * half + j) * HID + m];
            ahi[l][j] = (_Float16)Wl[qmap(16 + 8 * half + j) * HID + m];
        }
    }
    // input/output layer fragments in B-slot order, f16 pairs
    v2h win2[8], bin2[8], wout2[8];
#pragma unroll
    for (int u = 0; u < 8; ++u) {
        int i0 = 2 * u, i1 = 2 * u + 1;
        int d0 = qmap(((i0 >> 3) << 4) + 8 * half + (i0 & 7));
        int d1 = qmap(((i1 >> 3) << 4) + 8 * half + (i1 & 7));
        win2[u]  = v2h{(_Float16)W_in[d0],  (_Float16)W_in[d1]};
        bin2[u]  = v2h{(_Float16)b_in[d0],  (_Float16)b_in[d1]};
        wout2[u] = v2h{(_Float16)W_out[d0], (_Float16)W_out[d1]};
    }
    const float bo = b_out[0];
    const v2h slope2 = v2h{(_Float16)SLOPE, (_Float16)SLOPE};

    const int nwaves = (gridDim.x * blockDim.x) >> 6;
    const int wid    = (blockIdx.x * blockDim.x + threadIdx.x) >> 6;
    const int ntiles = (N + 31) >> 5;

    for (int tile = wid; tile < ntiles; tile += nwaves) {
        const int idx = tile * 32 + m;

        // ---- input layer (f16 packed math) ----
        float xv = (idx < N) ? x[idx] : 0.0f;
        _Float16 xh = (_Float16)xv;
        v2h x2 = v2h{xh, xh};
        v2h hp[8];
#pragma unroll
        for (int u = 0; u < 8; ++u) {
            v2h t = x2 * win2[u] + bin2[u];
            hp[u] = __builtin_elementwise_max(t, t * slope2);
        }

        // ---- 9 hidden layers ----
#pragma unroll
        for (int l = 0; l < NLAYERS; ++l) {
            v8h blo, bhi;
#pragma unroll
            for (int u = 0; u < 4; ++u) {
                blo[2 * u]     = hp[u][0];
                blo[2 * u + 1] = hp[u][1];
                bhi[2 * u]     = hp[4 + u][0];
                bhi[2 * u + 1] = hp[4 + u][1];
            }
            const float4* bp = (const float4*)&bias_sh[l][half][0];
            float4 c0 = bp[0], c1 = bp[1], c2 = bp[2], c3 = bp[3];
            v16f acc = {c0.x, c0.y, c0.z, c0.w, c1.x, c1.y, c1.z, c1.w,
                        c2.x, c2.y, c2.z, c2.w, c3.x, c3.y, c3.z, c3.w};
            acc = __builtin_amdgcn_mfma_f32_32x32x16_f16(alo[l], blo, acc, 0, 0, 0);
            acc = __builtin_amdgcn_mfma_f32_32x32x16_f16(ahi[l], bhi, acc, 0, 0, 0);
            // epilogue: leaky + cvt to f16; C reg r == B slot r by construction
#pragma unroll
            for (int u = 0; u < 8; ++u) {
                v2h t = pk_cvt(acc[2 * u], acc[2 * u + 1]);
                hp[u] = __builtin_elementwise_max(t, t * slope2);
            }
        }

        // ---- output layer: each half covers a disjoint 16 of the 32 dims ----
        float part = 0.0f;
#pragma unroll
        for (int u = 0; u < 8; ++u) {
            part = fmaf((float)hp[u][0], (float)wout2[u][0], part);
            part = fmaf((float)hp[u][1], (float)wout2[u][1], part);
        }
        float o = part + __shfl_xor(part, 32, 64) + bo;
        if (half == 0 && idx < N) out[idx] = o;
    }
}

extern "C" void kernel_launch(void* const* d_in, const int* in_sizes, int n_in,
                              void* d_out, int out_size, void* d_ws, size_t ws_size,
                              hipStream_t stream) {
    const float* x     = (const float*)d_in[0];
    const float* W_in  = (const float*)d_in[1];
    const float* b_in  = (const float*)d_in[2];
    const float* W_hid = (const float*)d_in[3];
    const float* b_hid = (const float*)d_in[4];
    const float* W_out = (const float*)d_in[5];
    const float* b_out = (const float*)d_in[6];
    float* out = (float*)d_out;

    int N = in_sizes[0];
    // 1024 blocks x 4 waves = 4096 waves; 32768 tiles -> 8 tiles/wave,
    // weights loaded once per wave and resident across the tile loop.
    dim3 block(256);
    dim3 grid(1024);
    mlp_mfma_kernel<<<grid, block, 0, stream>>>(x, W_in, b_in, W_hid, b_hid,
                                                W_out, b_out, out, N);
}

// Round 4
// 117.480 us; speedup vs baseline: 2.9453x; 1.0408x over previous
//
#include <hip/hip_runtime.h>

// Per-element MLP 1->32->(32x32)x9->1, leaky relu, v_mfma_f32_32x32x16_f16.
// R4: latency-hiding rewrite of R3 (which was 34% VALUBusy, latency-bound).
//  - activations ARE the B operand (union v8h/v2h) -> no pack movs
//  - bias: packed-f16 epilogue add; MFMA C = persistent zero regs
//  - bias from LDS as 2x ds_read_b128 f16 per layer, shared by both chains
//  - 2 independent batch tiles (chains) per wave; 512 blocks = exact residency
#define NLAYERS 9
#define HID 32
#define SLOPE 0.01f

typedef _Float16 v2h __attribute__((ext_vector_type(2)));
typedef _Float16 v8h __attribute__((ext_vector_type(8)));
typedef float v16f __attribute__((ext_vector_type(16)));

union U8 { v8h v; v2h p[4]; };          // B-operand half (16 f16 = 4 VGPRs)
struct B4 { v2h a, b, c, d; };           // 16B of packed bias

__device__ __forceinline__ v2h pk_cvt(float a, float b) {
    return __builtin_bit_cast(v2h, __builtin_amdgcn_cvt_pkrtz(a, b));
}
__device__ __forceinline__ v2h leaky2(v2h t, v2h s) {
    return __builtin_elementwise_max(t, t * s);
}
// B-operand physical slot k -> logical hidden unit (weight-side permutation)
__device__ __forceinline__ int qmap(int k) {
    int c = k >> 4, h = (k >> 3) & 1, t = k & 7;
    return 16 * c + 4 * h + (t & 3) + 8 * (t >> 2);
}
// C/D reg -> physical row
__device__ __forceinline__ int rmap(int reg, int h) {
    return (reg & 3) + 8 * (reg >> 2) + 4 * h;
}

__global__ __launch_bounds__(256) void mlp_mfma_kernel(
    const float* __restrict__ x,
    const float* __restrict__ W_in,   // [1,32]
    const float* __restrict__ b_in,   // [32]
    const float* __restrict__ W_hid,  // [9,32,32]  W[l][k_in][n_out]
    const float* __restrict__ b_hid,  // [9,32]
    const float* __restrict__ W_out,  // [32,1]
    const float* __restrict__ b_out,  // [1]
    float* __restrict__ out, int N)
{
    // packed f16 bias: [layer][half][j], pair j covers C regs (2j, 2j+1)
    __shared__ __align__(16) v2h bias_sh[NLAYERS][2][8];
    for (int t = threadIdx.x; t < NLAYERS * 16; t += blockDim.x) {
        int l = t >> 4, r = t & 15, h = r >> 3, j = r & 7;
        bias_sh[l][h][j] = v2h{(_Float16)b_hid[l * HID + rmap(2 * j, h)],
                               (_Float16)b_hid[l * HID + rmap(2 * j + 1, h)]};
    }
    __syncthreads();

    const int lane = threadIdx.x & 63;
    const int half = lane >> 5;
    const int m    = lane & 31;   // batch col within tile; also A output-row

    // ---- resident weight fragments ----
    v8h alo[NLAYERS], ahi[NLAYERS];
#pragma unroll
    for (int l = 0; l < NLAYERS; ++l) {
        const float* Wl = W_hid + l * HID * HID;
#pragma unroll
        for (int j = 0; j < 8; ++j) {
            alo[l][j] = (_Float16)Wl[qmap(8 * half + j) * HID + m];
            ahi[l][j] = (_Float16)Wl[qmap(16 + 8 * half + j) * HID + m];
        }
    }
    v2h win2[8], bin2[8], wout2[8];
#pragma unroll
    for (int u = 0; u < 8; ++u) {
        int i0 = 2 * u, i1 = 2 * u + 1;
        int d0 = qmap(((i0 >> 3) << 4) + 8 * half + (i0 & 7));
        int d1 = qmap(((i1 >> 3) << 4) + 8 * half + (i1 & 7));
        win2[u]  = v2h{(_Float16)W_in[d0],  (_Float16)W_in[d1]};
        bin2[u]  = v2h{(_Float16)b_in[d0],  (_Float16)b_in[d1]};
        wout2[u] = v2h{(_Float16)W_out[d0], (_Float16)W_out[d1]};
    }
    const float bo = b_out[0];
    const v2h slope2 = v2h{(_Float16)SLOPE, (_Float16)SLOPE};
    const v16f z16 = {};   // persistent zero C operand (never rewritten)

    const int nwaves = (gridDim.x * blockDim.x) >> 6;
    const int wid    = (blockIdx.x * blockDim.x + threadIdx.x) >> 6;
    const int niter  = (N + 63) >> 6;   // 64 batch elements per iteration

    for (int it = wid; it < niter; it += nwaves) {
        const int idx0 = it * 64 + m;
        const int idx1 = idx0 + 32;

        // ---- input layer, both chains ----
        float xv0 = (idx0 < N) ? x[idx0] : 0.0f;
        float xv1 = (idx1 < N) ? x[idx1] : 0.0f;
        _Float16 xh0 = (_Float16)xv0, xh1 = (_Float16)xv1;
        v2h x0 = v2h{xh0, xh0}, x1 = v2h{xh1, xh1};
        U8 c0lo, c0hi, c1lo, c1hi;
#pragma unroll
        for (int u = 0; u < 4; ++u) {
            c0lo.p[u] = leaky2(x0 * win2[u] + bin2[u], slope2);
            c0hi.p[u] = leaky2(x0 * win2[4 + u] + bin2[4 + u], slope2);
            c1lo.p[u] = leaky2(x1 * win2[u] + bin2[u], slope2);
            c1hi.p[u] = leaky2(x1 * win2[4 + u] + bin2[4 + u], slope2);
        }

        // ---- 9 hidden layers ----
#pragma unroll
        for (int l = 0; l < NLAYERS; ++l) {
            B4 q0 = __builtin_bit_cast(B4, ((const uint4*)&bias_sh[l][half][0])[0]);
            B4 q1 = __builtin_bit_cast(B4, ((const uint4*)&bias_sh[l][half][4])[0]);

            v16f a0 = __builtin_amdgcn_mfma_f32_32x32x16_f16(alo[l], c0lo.v, z16, 0, 0, 0);
            v16f a1 = __builtin_amdgcn_mfma_f32_32x32x16_f16(alo[l], c1lo.v, z16, 0, 0, 0);
            a0 = __builtin_amdgcn_mfma_f32_32x32x16_f16(ahi[l], c0hi.v, a0, 0, 0, 0);
            a1 = __builtin_amdgcn_mfma_f32_32x32x16_f16(ahi[l], c1hi.v, a1, 0, 0, 0);

            v2h bl[8] = {q0.a, q0.b, q0.c, q0.d, q1.a, q1.b, q1.c, q1.d};
#pragma unroll
            for (int u = 0; u < 4; ++u) {
                c0lo.p[u] = leaky2(pk_cvt(a0[2 * u], a0[2 * u + 1]) + bl[u], slope2);
                c1lo.p[u] = leaky2(pk_cvt(a1[2 * u], a1[2 * u + 1]) + bl[u], slope2);
                c0hi.p[u] = leaky2(pk_cvt(a0[8 + 2 * u], a0[8 + 2 * u + 1]) + bl[4 + u], slope2);
                c1hi.p[u] = leaky2(pk_cvt(a1[8 + 2 * u], a1[8 + 2 * u + 1]) + bl[4 + u], slope2);
            }
        }

        // ---- output layer (each half covers a disjoint 16 of 32 dims) ----
        float p0 = 0.0f, p1 = 0.0f;
#pragma unroll
        for (int u = 0; u < 4; ++u) {
            p0 = fmaf((float)c0lo.p[u][0], (float)wout2[u][0], p0);
            p0 = fmaf((float)c0lo.p[u][1], (float)wout2[u][1], p0);
            p0 = fmaf((float)c0hi.p[u][0], (float)wout2[4 + u][0], p0);
            p0 = fmaf((float)c0hi.p[u][1], (float)wout2[4 + u][1], p0);
            p1 = fmaf((float)c1lo.p[u][0], (float)wout2[u][0], p1);
            p1 = fmaf((float)c1lo.p[u][1], (float)wout2[u][1], p1);
            p1 = fmaf((float)c1hi.p[u][0], (float)wout2[4 + u][0], p1);
            p1 = fmaf((float)c1hi.p[u][1], (float)wout2[4 + u][1], p1);
        }
        float o0 = p0 + __shfl_xor(p0, 32, 64) + bo;
        float o1 = p1 + __shfl_xor(p1, 32, 64) + bo;
        if (half == 0) {
            if (idx0 < N) out[idx0] = o0;
            if (idx1 < N) out[idx1] = o1;
        }
    }
}

extern "C" void kernel_launch(void* const* d_in, const int* in_sizes, int n_in,
                              void* d_out, int out_size, void* d_ws, size_t ws_size,
                              hipStream_t stream) {
    const float* x     = (const float*)d_in[0];
    const float* W_in  = (const float*)d_in[1];
    const float* b_in  = (const float*)d_in[2];
    const float* W_hid = (const float*)d_in[3];
    const float* b_hid = (const float*)d_in[4];
    const float* W_out = (const float*)d_in[5];
    const float* b_out = (const float*)d_in[6];
    float* out = (float*)d_out;

    int N = in_sizes[0];
    // 512 blocks x 4 waves = 2048 waves = exactly 2 resident waves/SIMD.
    // 16384 dual-tile iterations -> 8 per wave; weights stay resident.
    dim3 block(256);
    dim3 grid(512);
    mlp_mfma_kernel<<<grid, block, 0, stream>>>(x, W_in, b_in, W_hid, b_hid,
                                                W_out, b_out, out, N);
}

// Round 5
// 96.150 us; speedup vs baseline: 3.5987x; 1.2218x over previous
//
#include <hip/hip_runtime.h>

// Per-element MLP 1->32->(32x32)x9->1, leaky relu, v_mfma_f32_32x32x16_f16.
// R5: R4 was latency-bound (9.3k cyc/iter vs 2.1k issue work) on dependent
// MFMA latency (~150cyc: mfma->mfma and mfma->VALU acc read) + unprefetched
// x loads. Fix: 4 independent chains/wave (8/SIMD) + cross-iter x prefetch.
// Weights stay VGPR-resident (LDS re-read would cost ~345 LDS cyc/iter).
#define NLAYERS 9
#define HID 32
#define SLOPE 0.01f

typedef _Float16 v2h __attribute__((ext_vector_type(2)));
typedef _Float16 v8h __attribute__((ext_vector_type(8)));
typedef float v16f __attribute__((ext_vector_type(16)));

#define NCHAIN 4

union U8 { v8h v; v2h p[4]; };          // B-operand half (16 f16 = 4 VGPRs)
struct B4 { v2h a, b, c, d; };           // 16B of packed bias

__device__ __forceinline__ v2h pk_cvt(float a, float b) {
    return __builtin_bit_cast(v2h, __builtin_amdgcn_cvt_pkrtz(a, b));
}
__device__ __forceinline__ v2h leaky2(v2h t, v2h s) {
    return __builtin_elementwise_max(t, t * s);
}
// B-operand physical slot k -> logical hidden unit (weight-side permutation)
__device__ __forceinline__ int qmap(int k) {
    int c = k >> 4, h = (k >> 3) & 1, t = k & 7;
    return 16 * c + 4 * h + (t & 3) + 8 * (t >> 2);
}
// C/D reg -> physical row
__device__ __forceinline__ int rmap(int reg, int h) {
    return (reg & 3) + 8 * (reg >> 2) + 4 * h;
}

__global__ __launch_bounds__(256, 2) void mlp_mfma_kernel(
    const float* __restrict__ x,
    const float* __restrict__ W_in,   // [1,32]
    const float* __restrict__ b_in,   // [32]
    const float* __restrict__ W_hid,  // [9,32,32]  W[l][k_in][n_out]
    const float* __restrict__ b_hid,  // [9,32]
    const float* __restrict__ W_out,  // [32,1]
    const float* __restrict__ b_out,  // [1]
    float* __restrict__ out, int N)
{
    // packed f16 bias: [layer][half][j], pair j covers C regs (2j, 2j+1)
    __shared__ __align__(16) v2h bias_sh[NLAYERS][2][8];
    for (int t = threadIdx.x; t < NLAYERS * 16; t += blockDim.x) {
        int l = t >> 4, r = t & 15, h = r >> 3, j = r & 7;
        bias_sh[l][h][j] = v2h{(_Float16)b_hid[l * HID + rmap(2 * j, h)],
                               (_Float16)b_hid[l * HID + rmap(2 * j + 1, h)]};
    }
    __syncthreads();

    const int lane = threadIdx.x & 63;
    const int half = lane >> 5;
    const int m    = lane & 31;   // batch col within tile; also A output-row

    // ---- resident weight fragments (72 VGPRs) ----
    v8h alo[NLAYERS], ahi[NLAYERS];
#pragma unroll
    for (int l = 0; l < NLAYERS; ++l) {
        const float* Wl = W_hid + l * HID * HID;
#pragma unroll
        for (int j = 0; j < 8; ++j) {
            alo[l][j] = (_Float16)Wl[qmap(8 * half + j) * HID + m];
            ahi[l][j] = (_Float16)Wl[qmap(16 + 8 * half + j) * HID + m];
        }
    }
    v2h win2[8], bin2[8], wout2[8];
#pragma unroll
    for (int u = 0; u < 8; ++u) {
        int i0 = 2 * u, i1 = 2 * u + 1;
        int d0 = qmap(((i0 >> 3) << 4) + 8 * half + (i0 & 7));
        int d1 = qmap(((i1 >> 3) << 4) + 8 * half + (i1 & 7));
        win2[u]  = v2h{(_Float16)W_in[d0],  (_Float16)W_in[d1]};
        bin2[u]  = v2h{(_Float16)b_in[d0],  (_Float16)b_in[d1]};
        wout2[u] = v2h{(_Float16)W_out[d0], (_Float16)W_out[d1]};
    }
    const float bo = b_out[0];
    const v2h slope2 = v2h{(_Float16)SLOPE, (_Float16)SLOPE};
    const v16f z16 = {};   // zero C operand (never rewritten)

    const int nwaves = (gridDim.x * blockDim.x) >> 6;
    const int wid    = (blockIdx.x * blockDim.x + threadIdx.x) >> 6;
    const int niter  = (N + NCHAIN * 32 - 1) / (NCHAIN * 32);

    // ---- x prefetch for first iteration ----
    float xc[NCHAIN] = {0.0f, 0.0f, 0.0f, 0.0f};
    if (wid < niter) {
#pragma unroll
        for (int c = 0; c < NCHAIN; ++c) {
            int idx = wid * (NCHAIN * 32) + c * 32 + m;
            xc[c] = (idx < N) ? x[idx] : 0.0f;
        }
    }

    for (int it = wid; it < niter; it += nwaves) {
        // prefetch next iteration's x (hides ~900cyc HBM latency under compute)
        float xn[NCHAIN] = {0.0f, 0.0f, 0.0f, 0.0f};
        {
            int nit = it + nwaves;
            if (nit < niter) {
#pragma unroll
                for (int c = 0; c < NCHAIN; ++c) {
                    int idx = nit * (NCHAIN * 32) + c * 32 + m;
                    xn[c] = (idx < N) ? x[idx] : 0.0f;
                }
            }
        }

        // ---- input layer, all chains ----
        U8 clo[NCHAIN], chi[NCHAIN];
#pragma unroll
        for (int c = 0; c < NCHAIN; ++c) {
            _Float16 xh = (_Float16)xc[c];
            v2h x2 = v2h{xh, xh};
#pragma unroll
            for (int u = 0; u < 4; ++u) {
                clo[c].p[u] = leaky2(x2 * win2[u] + bin2[u], slope2);
                chi[c].p[u] = leaky2(x2 * win2[4 + u] + bin2[4 + u], slope2);
            }
        }

        // ---- 9 hidden layers ----
#pragma unroll
        for (int l = 0; l < NLAYERS; ++l) {
            B4 q0 = __builtin_bit_cast(B4, ((const uint4*)&bias_sh[l][half][0])[0]);
            B4 q1 = __builtin_bit_cast(B4, ((const uint4*)&bias_sh[l][half][4])[0]);

            v16f a[NCHAIN];
            // lo MFMAs first (independent), then hi (each dependent on its lo
            // but ~3 other MFMAs in between -> latency hidden in-pipe)
#pragma unroll
            for (int c = 0; c < NCHAIN; ++c)
                a[c] = __builtin_amdgcn_mfma_f32_32x32x16_f16(alo[l], clo[c].v, z16, 0, 0, 0);
#pragma unroll
            for (int c = 0; c < NCHAIN; ++c)
                a[c] = __builtin_amdgcn_mfma_f32_32x32x16_f16(ahi[l], chi[c].v, a[c], 0, 0, 0);

            v2h bl[8] = {q0.a, q0.b, q0.c, q0.d, q1.a, q1.b, q1.c, q1.d};
#pragma unroll
            for (int c = 0; c < NCHAIN; ++c) {
#pragma unroll
                for (int u = 0; u < 4; ++u) {
                    clo[c].p[u] = leaky2(pk_cvt(a[c][2 * u], a[c][2 * u + 1]) + bl[u], slope2);
                    chi[c].p[u] = leaky2(pk_cvt(a[c][8 + 2 * u], a[c][8 + 2 * u + 1]) + bl[4 + u], slope2);
                }
            }
        }

        // ---- output layer ----
#pragma unroll
        for (int c = 0; c < NCHAIN; ++c) {
            float p = 0.0f;
#pragma unroll
            for (int u = 0; u < 4; ++u) {
                p = fmaf((float)clo[c].p[u][0], (float)wout2[u][0], p);
                p = fmaf((float)clo[c].p[u][1], (float)wout2[u][1], p);
                p = fmaf((float)chi[c].p[u][0], (float)wout2[4 + u][0], p);
                p = fmaf((float)chi[c].p[u][1], (float)wout2[4 + u][1], p);
            }
            float o = p + __shfl_xor(p, 32, 64) + bo;   // full sum in all lanes
            int idx = it * (NCHAIN * 32) + c * 32 + m;
            // split the 4 stores across the two halves (2 per lane)
            if (half == (c >> 1) && idx < N) out[idx] = o;
        }

#pragma unroll
        for (int c = 0; c < NCHAIN; ++c) xc[c] = xn[c];
    }
}

extern "C" void kernel_launch(void* const* d_in, const int* in_sizes, int n_in,
                              void* d_out, int out_size, void* d_ws, size_t ws_size,
                              hipStream_t stream) {
    const float* x     = (const float*)d_in[0];
    const float* W_in  = (const float*)d_in[1];
    const float* b_in  = (const float*)d_in[2];
    const float* W_hid = (const float*)d_in[3];
    const float* b_hid = (const float*)d_in[4];
    const float* W_out = (const float*)d_in[5];
    const float* b_out = (const float*)d_in[6];
    float* out = (float*)d_out;

    int N = in_sizes[0];
    // 512 blocks x 4 waves = 2048 waves = 2 waves/SIMD resident.
    // 8192 quad-tile iterations -> 4 per wave; weights stay resident.
    dim3 block(256);
    dim3 grid(512);
    mlp_mfma_kernel<<<grid, block, 0, stream>>>(x, W_in, b_in, W_hid, b_hid,
                                                W_out, b_out, out, N);
}